// Round 13
// baseline (40.368 us; speedup 1.0000x reference)
//
#include <hip/hip_runtime.h>
#include <stdint.h>

// Problem constants (from reference):
#define T_DIM 1024
#define B_DIM 8
#define C_DIM 1024
#define H_DIM 16
#define K_SZ  7
#define P_PAD 3
#define O_DIM (H_DIM * K_SZ)   // 112
#define TB    (T_DIM * B_DIM)  // 8192 rows

typedef __attribute__((ext_vector_type(8))) short bf16x8;  // 4 VGPRs, 8 bf16
typedef __attribute__((ext_vector_type(4))) float f32x4;

union FragU { uint32_t u[4]; bf16x8 v; };

// RNE fp32->bf16 pack of two floats into one dword (lo=a, hi=b)
__device__ inline uint32_t pk_bf16(float a, float b) {
  uint32_t ua = __float_as_uint(a), ub = __float_as_uint(b);
  ua += 0x7FFFu + ((ua >> 16) & 1u);
  ub += 0x7FFFu + ((ub >> 16) & 1u);
  return (ua >> 16) | (ub & 0xFFFF0000u);
}

__device__ inline bf16x8 cvt8(f32x4 lo, f32x4 hi) {
  FragU f;
  f.u[0] = pk_bf16(lo[0], lo[1]);
  f.u[1] = pk_bf16(lo[2], lo[3]);
  f.u[2] = pk_bf16(hi[0], hi[1]);
  f.u[3] = pk_bf16(hi[2], hi[3]);
  return f.v;
}

__device__ inline bf16x8 load_bf16x8_cvt(const float* __restrict__ p) {
  f32x4 lo = *reinterpret_cast<const f32x4*>(p);
  f32x4 hi = *reinterpret_cast<const f32x4*>(p + 4);
  return cvt8(lo, hi);
}

// Kernel 0: build fragment-native bf16 W.
// Wf[((ks*7)+nf)*64 + lane] (16B) = W[nf*16+(lane&15)][ks*32+(lane>>4)*8 .. +7]
__global__ __launch_bounds__(256) void prep_wfrag_kernel(
    const float* __restrict__ Wl, uint16_t* __restrict__ Wf) {
  const int t  = blockIdx.x * 256 + threadIdx.x;  // 0..14335
  const int f  = t >> 6;
  const int l  = t & 63;
  const int ks = f / 7;
  const int nf = f - ks * 7;
  const int row = nf * 16 + (l & 15);
  const int kb  = ks * 32 + (l >> 4) * 8;
  bf16x8 v = load_bf16x8_cvt(Wl + (size_t)row * C_DIM + kb);
  *reinterpret_cast<bf16x8*>(Wf + (size_t)t * 8) = v;   // coalesced 16B/lane
}

// Kernel 1: w = softmax_K( x @ W^T + b ). 512 blocks x 512 threads, ALL
// co-resident (2 blocks/CU, 16 waves/CU). Block = 16 rows; wave wv owns
// K-eighth [wv*128, wv*128+128): loads A straight from global into regs
// (no LDS staging, no load->MFMA barrier; 8 independent float4 loads
// issued up-front), A reused across all 7 nf from registers -> x read
// exactly once (32MB HBM total). part[8] LDS reduce + softmax + coalesced
// wbuf stores.
template <bool PREPPED>
__global__ __launch_bounds__(512, 4) void logits_kernel(
    const float* __restrict__ x, const float* __restrict__ Wl,
    const uint16_t* __restrict__ Wf, const float* __restrict__ bl,
    float* __restrict__ wbuf) {
  __shared__ float part[8][16][116];   // 59.4KB: per-K-eighth logits
  __shared__ float wsm[16][112];       // 7.2KB: softmax weights (unpadded)

  const int tid  = threadIdx.x;
  const int wv   = tid >> 6;           // 0..7 = K-eighth
  const int lane = tid & 63;
  const int l15  = lane & 15;
  const int oct  = lane >> 4;
  const int rb   = blockIdx.x * 16;

  {
    f32x4 acc[7];
#pragma unroll
    for (int nf = 0; nf < 7; ++nf) acc[nf] = (f32x4)(0.f);

    const float* __restrict__ xr =
        x + (size_t)(rb + l15) * C_DIM + wv * 128 + oct * 8;
#pragma unroll
    for (int s = 0; s < 4; ++s) {
      bf16x8 a = load_bf16x8_cvt(xr + s * 32);
      const int ksg = wv * 4 + s;
#pragma unroll
      for (int nf = 0; nf < 7; ++nf) {
        bf16x8 bf;
        if (PREPPED)
          bf = *reinterpret_cast<const bf16x8*>(
              Wf + ((size_t)((ksg * 7 + nf) * 64) + lane) * 8);
        else
          bf = load_bf16x8_cvt(
              Wl + (size_t)(nf * 16 + l15) * C_DIM + ksg * 32 + oct * 8);
        acc[nf] = __builtin_amdgcn_mfma_f32_16x16x32_bf16(a, bf, acc[nf], 0, 0, 0);
      }
    }
    // D layout: col = lane&15 (W row), row = (lane>>4)*4 + reg (x row)
#pragma unroll
    for (int nf = 0; nf < 7; ++nf)
#pragma unroll
      for (int rr = 0; rr < 4; ++rr)
        part[wv][oct * 4 + rr][nf * 16 + l15] = acc[nf][rr];
  }
  __syncthreads();

  // reduce 8 partials + bias + softmax (first 4 waves; 16 rows x 16 heads)
  if (tid < 256) {
    const int row = tid >> 4;
    const int h   = tid & 15;
    float lg[7];
    float m = -1e30f;
#pragma unroll
    for (int j = 0; j < 7; ++j) {
      const int c = h * 7 + j;
      float s_ = bl[c];
#pragma unroll
      for (int kh = 0; kh < 8; ++kh) s_ += part[kh][row][c];
      lg[j] = s_;
      m = fmaxf(m, s_);
    }
    float s = 0.f;
#pragma unroll
    for (int j = 0; j < 7; ++j) { lg[j] = __expf(lg[j] - m); s += lg[j]; }
    const float inv = 1.0f / s;
#pragma unroll
    for (int j = 0; j < 7; ++j) wsm[row][h * 7 + j] = lg[j] * inv;
  }
  __syncthreads();

  // coalesced wbuf write: 16 rows x 112 = 448 float4; threads 0..447
  if (tid < 448) {
    const int row = tid / 28;            // 28 float4 per row
    const int c4  = (tid - row * 28) * 4;
    f32x4 v;
    v[0] = wsm[row][c4 + 0];
    v[1] = wsm[row][c4 + 1];
    v[2] = wsm[row][c4 + 2];
    v[3] = wsm[row][c4 + 3];
    *reinterpret_cast<f32x4*>(wbuf + (size_t)(rb + row) * O_DIM + c4) = v;
  }
}

// Kernel 2 (round-1 proven, ~10.7us ~= HBM floor):
// out[t,b,c] = sum_j w[t,b,h(c),j] * x[t-3+j, b, c] + bias[c]
__global__ __launch_bounds__(256) void dynconv_kernel(
    const float* __restrict__ x, const float* __restrict__ w,
    const float* __restrict__ bias, float* __restrict__ out) {
  const int row = blockIdx.x;   // t*B + b
  const int t   = row >> 3;
  const int b   = row & 7;
  const int tid = threadIdx.x;
  const int c4  = tid << 2;
  const int h   = c4 >> 6;      // R = 64 channels per head
  const float* __restrict__ wr = w + (size_t)row * O_DIM + h * K_SZ;

  float ax = 0.f, ay = 0.f, az = 0.f, aw = 0.f;
#pragma unroll
  for (int j = 0; j < K_SZ; ++j) {
    int st = t - P_PAD + j;
    if (st < 0 || st >= T_DIM) continue;
    float wj = wr[j];
    const float4 xv = *reinterpret_cast<const float4*>(
        x + ((size_t)(st * B_DIM + b)) * C_DIM + c4);
    ax += wj * xv.x;
    ay += wj * xv.y;
    az += wj * xv.z;
    aw += wj * xv.w;
  }
  float4 bv = *reinterpret_cast<const float4*>(bias + c4);
  float4 o4 = make_float4(ax + bv.x, ay + bv.y, az + bv.z, aw + bv.w);
  *reinterpret_cast<float4*>(out + (size_t)row * C_DIM + c4) = o4;
}

extern "C" void kernel_launch(void* const* d_in, const int* in_sizes, int n_in,
                              void* d_out, int out_size, void* d_ws, size_t ws_size,
                              hipStream_t stream) {
  const float* x  = (const float*)d_in[0];   // (T,B,C)
  const float* Wl = (const float*)d_in[1];   // (H*K, C)
  const float* bl = (const float*)d_in[2];   // (H*K,)
  const float* cb = (const float*)d_in[3];   // (C,)
  float* out = (float*)d_out;                // (T,B,C)

  const size_t WF_BYTES   = 262144;                    // 224KB frag-W, padded
  const size_t WBUF_BYTES = (size_t)TB * O_DIM * 4;    // 3.67 MB
  const bool prepped = ws_size >= WF_BYTES + WBUF_BYTES;

  if (prepped) {
    uint16_t* wf = (uint16_t*)d_ws;
    float* wbuf  = (float*)((char*)d_ws + WF_BYTES);
    prep_wfrag_kernel<<<(32 * 7 * 64) / 256, 256, 0, stream>>>(Wl, wf);
    logits_kernel<true><<<TB / 16, 512, 0, stream>>>(x, Wl, wf, bl, wbuf);
    dynconv_kernel<<<TB, 256, 0, stream>>>(x, wbuf, cb, out);
  } else {
    float* wbuf = (float*)d_ws;
    logits_kernel<false><<<TB / 16, 512, 0, stream>>>(x, Wl, nullptr, bl, wbuf);
    dynconv_kernel<<<TB, 256, 0, stream>>>(x, wbuf, cb, out);
  }
}

// Round 14
// 36.317 us; speedup vs baseline: 1.1116x; 1.1116x over previous
//
#include <hip/hip_runtime.h>
#include <stdint.h>

// Problem constants (from reference):
#define T_DIM 1024
#define B_DIM 8
#define C_DIM 1024
#define H_DIM 16
#define K_SZ  7
#define P_PAD 3
#define O_DIM (H_DIM * K_SZ)   // 112
#define TB    (T_DIM * B_DIM)  // 8192 rows

// LDS x-tile row stride in bytes: 1024 bf16 + 16B pad.
#define XSTRIDE 2064

typedef __attribute__((ext_vector_type(8))) short bf16x8;  // 4 VGPRs, 8 bf16
typedef __attribute__((ext_vector_type(4))) float f32x4;
typedef __attribute__((ext_vector_type(2))) uint32_t u32x2;

union FragU { uint32_t u[4]; bf16x8 v; };

// RNE fp32->bf16 pack of two floats into one dword (lo=a, hi=b)
__device__ inline uint32_t pk_bf16(float a, float b) {
  uint32_t ua = __float_as_uint(a), ub = __float_as_uint(b);
  ua += 0x7FFFu + ((ua >> 16) & 1u);
  ub += 0x7FFFu + ((ub >> 16) & 1u);
  return (ua >> 16) | (ub & 0xFFFF0000u);
}

__device__ inline bf16x8 load_bf16x8_cvt(const float* __restrict__ p) {
  f32x4 lo = *reinterpret_cast<const f32x4*>(p);
  f32x4 hi = *reinterpret_cast<const f32x4*>(p + 4);
  FragU f;
  f.u[0] = pk_bf16(lo[0], lo[1]);
  f.u[1] = pk_bf16(lo[2], lo[3]);
  f.u[2] = pk_bf16(hi[0], hi[1]);
  f.u[3] = pk_bf16(hi[2], hi[3]);
  return f.v;
}

// Kernel 0: build fragment-native bf16 W.
// Wf[((ks*7)+nf)*64 + lane] (16B) = W[nf*16+(lane&15)][ks*32+(lane>>4)*8 .. +7]
__global__ __launch_bounds__(256) void prep_wfrag_kernel(
    const float* __restrict__ Wl, uint16_t* __restrict__ Wf) {
  const int t  = blockIdx.x * 256 + threadIdx.x;  // 0..14335
  const int f  = t >> 6;
  const int l  = t & 63;
  const int ks = f / 7;
  const int nf = f - ks * 7;
  const int row = nf * 16 + (l & 15);
  const int kb  = ks * 32 + (l >> 4) * 8;
  bf16x8 v = load_bf16x8_cvt(Wl + (size_t)row * C_DIM + kb);
  *reinterpret_cast<bf16x8*>(Wf + (size_t)t * 8) = v;   // coalesced 16B/lane
}

// Fused kernel: 1024 SMALL INDEPENDENT blocks x 256 threads (4 waves).
// Block = one t0 x all 8 batches: x slice is 32KB CONTIGUOUS.
// 4 blocks/CU co-resident (24KB LDS, <=128 VGPR) -> 16 waves/CU with
// cross-BLOCK latency overlap (different blocks in different phases),
// mimicking the only kernel that ever hit its roofline here (r1 conv:
// 8192 independent blocks). Only 3 thin barriers per short-lived block.
//  phase 1: stage 8 rows -> bf16 LDS (coalesced, 4KB/wave-instr)
//  phase 2: wave wv computes nf{2wv,2wv+1} over FULL K (no partial reduce)
//  phase 3: softmax (threads 0..127)
//  phase 4: conv; taps fp32 straight from global (L2-hot), coalesced out
template <bool PREPPED>
__global__ __launch_bounds__(256, 4) void fused8_kernel(
    const float* __restrict__ x, const float* __restrict__ Wl,
    const uint16_t* __restrict__ Wf, const float* __restrict__ bl,
    const float* __restrict__ cb, float* __restrict__ out) {
  __shared__ char  xbf[8 * XSTRIDE];   // 16.5KB: bf16 x tile (t0, all b)
  __shared__ float lg[8][116];         // 3.7KB: logits
  __shared__ float wsm[8][116];        // 3.7KB: softmax weights

  const int tid  = threadIdx.x;
  const int wv   = tid >> 6;           // 0..3
  const int lane = tid & 63;
  const int l15  = lane & 15;
  const int oct  = lane >> 4;

  // XCD swizzle (bijective, 1024 = 8*128): each XCD gets contiguous t-range
  const int bid = blockIdx.x;
  const int t0  = (bid & 7) * 128 + (bid >> 3);

  const float* __restrict__ xrow0 = x + (size_t)t0 * B_DIM * C_DIM; // 32KB

  // --- phase 1: stage 8 rows -> bf16 LDS; iteration it = row (b) ---
#pragma unroll
  for (int it = 0; it < 8; ++it) {
    f32x4 v = *reinterpret_cast<const f32x4*>(xrow0 + it * C_DIM + tid * 4);
    u32x2 d;
    d.x = pk_bf16(v[0], v[1]);
    d.y = pk_bf16(v[2], v[3]);
    *reinterpret_cast<u32x2*>(xbf + it * XSTRIDE + tid * 8) = d;
  }
  __syncthreads();

  // --- phase 2: MFMA, wave wv -> nf {2wv, 2wv+1} (wv=3: nf 6 only), full K ---
  {
    const int nf0 = wv * 2;
    const int nfc = (wv == 3) ? 1 : 2;
    f32x4 acc0 = (f32x4)(0.f), acc1 = (f32x4)(0.f);
    const char* __restrict__ arow = xbf + (l15 & 7) * XSTRIDE;  // rows dup'd 8..15
#pragma unroll
    for (int ks = 0; ks < 32; ++ks) {
      bf16x8 a = *reinterpret_cast<const bf16x8*>(arow + ks * 64 + oct * 16);
      bf16x8 b0, b1;
      if (PREPPED) {
        b0 = *reinterpret_cast<const bf16x8*>(
            Wf + ((size_t)((ks * 7 + nf0) * 64) + lane) * 8);
        if (nfc == 2)
          b1 = *reinterpret_cast<const bf16x8*>(
              Wf + ((size_t)((ks * 7 + nf0 + 1) * 64) + lane) * 8);
      } else {
        b0 = load_bf16x8_cvt(Wl + (size_t)(nf0 * 16 + l15) * C_DIM + ks * 32 + oct * 8);
        if (nfc == 2)
          b1 = load_bf16x8_cvt(Wl + (size_t)((nf0 + 1) * 16 + l15) * C_DIM + ks * 32 + oct * 8);
      }
      acc0 = __builtin_amdgcn_mfma_f32_16x16x32_bf16(a, b0, acc0, 0, 0, 0);
      if (nfc == 2)
        acc1 = __builtin_amdgcn_mfma_f32_16x16x32_bf16(a, b1, acc1, 0, 0, 0);
    }
    // D layout: col = lane&15 (W row), row = oct*4+reg (x row); rows 8..15
    // are duplicates of 0..7 (A rows duplicated) -> store only oct<2.
    if (oct < 2) {
#pragma unroll
      for (int rr = 0; rr < 4; ++rr)
        lg[oct * 4 + rr][nf0 * 16 + l15] = acc0[rr];
      if (nfc == 2) {
#pragma unroll
        for (int rr = 0; rr < 4; ++rr)
          lg[oct * 4 + rr][(nf0 + 1) * 16 + l15] = acc1[rr];
      }
    }
  }
  __syncthreads();

  // --- phase 3: bias + softmax over 7 taps (threads 0..127) ---
  if (tid < 128) {
    const int row = tid >> 4;
    const int h   = tid & 15;
    float v[7];
    float m = -1e30f;
#pragma unroll
    for (int j = 0; j < 7; ++j) {
      float s_ = lg[row][h * 7 + j] + bl[h * 7 + j];
      v[j] = s_;
      m = fmaxf(m, s_);
    }
    float s = 0.f;
#pragma unroll
    for (int j = 0; j < 7; ++j) { v[j] = __expf(v[j] - m); s += v[j]; }
    const float inv = 1.0f / s;
#pragma unroll
    for (int j = 0; j < 7; ++j) wsm[row][h * 7 + j] = v[j] * inv;
  }
  __syncthreads();

  // --- phase 4: conv; thread = (b = tid>>5, lane32 = tid&31) ---
  {
    const int b    = tid >> 5;
    const int l32  = tid & 31;
    const int grow = t0 * B_DIM + b;
    const float* __restrict__ tp[7];
    float okf[7];
#pragma unroll
    for (int j = 0; j < 7; ++j) {
      const int t_ = t0 + j - P_PAD;
      okf[j] = (t_ >= 0 && t_ < T_DIM) ? 1.f : 0.f;
      const int g = min(max(t_, 0), T_DIM - 1);
      tp[j] = x + ((size_t)(g * B_DIM + b)) * C_DIM;
    }
    float* __restrict__ obase = out + (size_t)grow * C_DIM;
#pragma unroll
    for (int cc = 0; cc < 8; ++cc) {
      const int ch   = l32 * 4 + cc * 128;   // lanes contiguous 512B segments
      const int head = ch >> 6;
      const float* __restrict__ wr = &wsm[b][head * 7];
      f32x4 a = *reinterpret_cast<const f32x4*>(cb + ch);
#pragma unroll
      for (int j = 0; j < 7; ++j) {
        f32x4 d = *reinterpret_cast<const f32x4*>(tp[j] + ch);
        a += (wr[j] * okf[j]) * d;
      }
      *reinterpret_cast<f32x4*>(obase + ch) = a;
    }
  }
}

extern "C" void kernel_launch(void* const* d_in, const int* in_sizes, int n_in,
                              void* d_out, int out_size, void* d_ws, size_t ws_size,
                              hipStream_t stream) {
  const float* x  = (const float*)d_in[0];   // (T,B,C)
  const float* Wl = (const float*)d_in[1];   // (H*K, C)
  const float* bl = (const float*)d_in[2];   // (H*K,)
  const float* cb = (const float*)d_in[3];   // (C,)
  float* out = (float*)d_out;                // (T,B,C)

  const bool prepped = ws_size >= 262144;    // 224KB frag-W, padded

  if (prepped) {
    uint16_t* wf = (uint16_t*)d_ws;
    prep_wfrag_kernel<<<(32 * 7 * 64) / 256, 256, 0, stream>>>(Wl, wf);
    fused8_kernel<true><<<T_DIM, 256, 0, stream>>>(x, Wl, wf, bl, cb, out);
  } else {
    fused8_kernel<false><<<T_DIM, 256, 0, stream>>>(x, Wl, nullptr, bl, cb, out);
  }
}